// Round 1
// baseline (10197.180 us; speedup 1.0000x reference)
//
#include <hip/hip_runtime.h>
#include <hip/hip_bf16.h>

// Problem dims (fixed by reference)
#define N_USERS  50000
#define N_ITEMS  100000
#define N_GROUPS 20000
#define DIM      128
#define TWO_DIM  256
#define N_FULL   (N_USERS + N_ITEMS)   // 150000

// ---------------------------------------------------------------------------
// SpMM scatter: out[rows[e], :] += vals[e] * dense[cols[e], :]
// 32 lanes per nnz, each lane handles a float4 (128 floats total).
// ---------------------------------------------------------------------------
__global__ __launch_bounds__(256) void spmm_atomic(
    const int* __restrict__ rows, const int* __restrict__ cols,
    const float* __restrict__ vals, const float* __restrict__ dense,
    float* __restrict__ out, int nnz)
{
    long long t = (long long)blockIdx.x * blockDim.x + threadIdx.x;
    int e    = (int)(t >> 5);
    int lane = (int)(t & 31);
    if (e >= nnz) return;
    int   r = rows[e];
    int   c = cols[e];
    float v = vals[e];
    float4 x = ((const float4*)(dense + (size_t)c * DIM))[lane];
    float* dst = out + (size_t)r * DIM + lane * 4;
    atomicAdd(dst + 0, v * x.x);
    atomicAdd(dst + 1, v * x.y);
    atomicAdd(dst + 2, v * x.z);
    atomicAdd(dst + 3, v * x.w);
}

// ---------------------------------------------------------------------------
// Dense layer: msg[g, d] = b[d] + sum_k concat(um,im)[g, k] * W[d, k]
// W is [128, 256] row-major. Tiled: 32 rows/block, 256 threads,
// each thread computes 2 rows x 8 cols. k-chunks of 64.
// ---------------------------------------------------------------------------
__global__ __launch_bounds__(256) void dense_agg(
    const float* __restrict__ um, const float* __restrict__ im,
    const float* __restrict__ W, const float* __restrict__ b,
    float* __restrict__ msg)
{
    __shared__ float As[32][68];    // 32 rows x 64 k (pad to 68 for alignment)
    __shared__ float Ws[64][132];   // k x d (transposed W chunk), pad 132

    int tid = threadIdx.x;
    int tx  = tid & 15;    // d-group: d = tx*8 .. tx*8+7
    int ty  = tid >> 4;    // row-group: r = ty*2, ty*2+1
    int rowBase = blockIdx.x * 32;

    float acc[2][8];
#pragma unroll
    for (int i = 0; i < 2; ++i)
#pragma unroll
        for (int j = 0; j < 8; ++j) acc[i][j] = 0.f;

    for (int kc = 0; kc < 4; ++kc) {
        int k0 = kc * 64;
        const float* Asrc = (k0 < DIM) ? um : im;
        int kOff = (k0 < DIM) ? k0 : (k0 - DIM);

        // stage A tile: 32 rows x 16 float4 = 512 float4, 2 per thread
#pragma unroll
        for (int l = 0; l < 2; ++l) {
            int idx = tid + l * 256;      // 0..511
            int r   = idx >> 4;           // 0..31
            int kq  = idx & 15;           // 0..15
            int gRow = rowBase + r;
            float4 v = make_float4(0.f, 0.f, 0.f, 0.f);
            if (gRow < N_GROUPS)
                v = *(const float4*)(Asrc + (size_t)gRow * DIM + kOff + kq * 4);
            *(float4*)&As[r][kq * 4] = v;
        }
        // stage W chunk transposed: Ws[k][d] = W[d*256 + k0 + k]
#pragma unroll
        for (int l = 0; l < 8; ++l) {
            int idx = tid + l * 256;      // 0..2047
            int d   = idx >> 4;           // 0..127
            int kq  = idx & 15;           // 0..15
            float4 v = *(const float4*)(W + (size_t)d * TWO_DIM + k0 + kq * 4);
            Ws[kq * 4 + 0][d] = v.x;
            Ws[kq * 4 + 1][d] = v.y;
            Ws[kq * 4 + 2][d] = v.z;
            Ws[kq * 4 + 3][d] = v.w;
        }
        __syncthreads();

        int ty2 = ty * 2;
        int tx8 = tx * 8;
#pragma unroll 8
        for (int k = 0; k < 64; ++k) {
            float a0 = As[ty2 + 0][k];
            float a1 = As[ty2 + 1][k];
            float4 w0 = *(const float4*)&Ws[k][tx8];
            float4 w1 = *(const float4*)&Ws[k][tx8 + 4];
            acc[0][0] = fmaf(a0, w0.x, acc[0][0]);
            acc[0][1] = fmaf(a0, w0.y, acc[0][1]);
            acc[0][2] = fmaf(a0, w0.z, acc[0][2]);
            acc[0][3] = fmaf(a0, w0.w, acc[0][3]);
            acc[0][4] = fmaf(a0, w1.x, acc[0][4]);
            acc[0][5] = fmaf(a0, w1.y, acc[0][5]);
            acc[0][6] = fmaf(a0, w1.z, acc[0][6]);
            acc[0][7] = fmaf(a0, w1.w, acc[0][7]);
            acc[1][0] = fmaf(a1, w0.x, acc[1][0]);
            acc[1][1] = fmaf(a1, w0.y, acc[1][1]);
            acc[1][2] = fmaf(a1, w0.z, acc[1][2]);
            acc[1][3] = fmaf(a1, w0.w, acc[1][3]);
            acc[1][4] = fmaf(a1, w1.x, acc[1][4]);
            acc[1][5] = fmaf(a1, w1.y, acc[1][5]);
            acc[1][6] = fmaf(a1, w1.z, acc[1][6]);
            acc[1][7] = fmaf(a1, w1.w, acc[1][7]);
        }
        __syncthreads();
    }

    int d0 = tx * 8;
    float4 bv0 = *(const float4*)(b + d0);
    float4 bv1 = *(const float4*)(b + d0 + 4);
#pragma unroll
    for (int i = 0; i < 2; ++i) {
        int gRow = rowBase + ty * 2 + i;
        if (gRow < N_GROUPS) {
            float4 o0 = make_float4(acc[i][0] + bv0.x, acc[i][1] + bv0.y,
                                    acc[i][2] + bv0.z, acc[i][3] + bv0.w);
            float4 o1 = make_float4(acc[i][4] + bv1.x, acc[i][5] + bv1.y,
                                    acc[i][6] + bv1.z, acc[i][7] + bv1.w);
            *(float4*)(msg + (size_t)gRow * DIM + d0)     = o0;
            *(float4*)(msg + (size_t)gRow * DIM + d0 + 4) = o1;
        }
    }
}

// ---------------------------------------------------------------------------
extern "C" void kernel_launch(void* const* d_in, const int* in_sizes, int n_in,
                              void* d_out, int out_size, void* d_ws, size_t ws_size,
                              hipStream_t stream)
{
    const float* user_emb = (const float*)d_in[0];
    const float* item_emb = (const float*)d_in[1];
    // d_in[2] group_emb: unused by the reference
    const int*   u_rows = (const int*)d_in[3];
    const int*   u_cols = (const int*)d_in[4];
    const float* u_vals = (const float*)d_in[5];
    const int*   i_rows = (const int*)d_in[6];
    const int*   i_cols = (const int*)d_in[7];
    const float* i_vals = (const float*)d_in[8];
    const int*   f_rows = (const int*)d_in[9];
    const int*   f_cols = (const int*)d_in[10];
    const float* f_vals = (const float*)d_in[11];
    const float* W      = (const float*)d_in[12];
    const float* bias   = (const float*)d_in[13];

    int nnz_u = in_sizes[3];
    int nnz_i = in_sizes[6];
    int nnz_f = in_sizes[9];

    float* out  = (float*)d_out;
    float* norm = out;                                   // [150000, 128]
    float* msg  = out + (size_t)N_FULL * DIM;            // [20000, 128]

    // Use the front of the norm region as scratch for um/im (disjoint from msg).
    float* um = norm;
    float* im = norm + (size_t)N_GROUPS * DIM;

    // Zero norm region (covers um/im scratch too).
    hipMemsetAsync(norm, 0, (size_t)N_FULL * DIM * sizeof(float), stream);

    auto spmm_blocks = [](int nnz) {
        return (unsigned)(((long long)nnz * 32 + 255) / 256);
    };

    spmm_atomic<<<spmm_blocks(nnz_u), 256, 0, stream>>>(
        u_rows, u_cols, u_vals, user_emb, um, nnz_u);
    spmm_atomic<<<spmm_blocks(nnz_i), 256, 0, stream>>>(
        i_rows, i_cols, i_vals, item_emb, im, nnz_i);

    dense_agg<<<(N_GROUPS + 31) / 32, 256, 0, stream>>>(um, im, W, bias, msg);

    // Re-zero the scratch portion before the final scatter accumulates there.
    hipMemsetAsync(norm, 0, (size_t)2 * N_GROUPS * DIM * sizeof(float), stream);

    spmm_atomic<<<spmm_blocks(nnz_f), 256, 0, stream>>>(
        f_rows, f_cols, f_vals, msg, norm, nnz_f);
}

// Round 2
// 1508.123 us; speedup vs baseline: 6.7615x; 6.7615x over previous
//
#include <hip/hip_runtime.h>
#include <hip/hip_bf16.h>
#include <stdint.h>

// Problem dims (fixed by reference)
#define N_USERS  50000
#define N_ITEMS  100000
#define N_GROUPS 20000
#define DIM      128
#define TWO_DIM  256
#define N_FULL   (N_USERS + N_ITEMS)   // 150000

// ---------------------------------------------------------------------------
// Fallback path (R1): SpMM scatter with f32 atomics.
// ---------------------------------------------------------------------------
__global__ __launch_bounds__(256) void spmm_atomic(
    const int* __restrict__ rows, const int* __restrict__ cols,
    const float* __restrict__ vals, const float* __restrict__ dense,
    float* __restrict__ out, int nnz)
{
    long long t = (long long)blockIdx.x * blockDim.x + threadIdx.x;
    int e    = (int)(t >> 5);
    int lane = (int)(t & 31);
    if (e >= nnz) return;
    int   r = rows[e];
    int   c = cols[e];
    float v = vals[e];
    float4 x = ((const float4*)(dense + (size_t)c * DIM))[lane];
    float* dst = out + (size_t)r * DIM + lane * 4;
    atomicAdd(dst + 0, v * x.x);
    atomicAdd(dst + 1, v * x.y);
    atomicAdd(dst + 2, v * x.z);
    atomicAdd(dst + 3, v * x.w);
}

// ---------------------------------------------------------------------------
// CSR build step 1: histogram of row ids (int atomics).
// ---------------------------------------------------------------------------
__global__ __launch_bounds__(256) void hist_rows(
    const int* __restrict__ rows, int nnz, int* __restrict__ cnt)
{
    int e = blockIdx.x * blockDim.x + threadIdx.x;
    if (e < nnz) atomicAdd(&cnt[rows[e]], 1);
}

// ---------------------------------------------------------------------------
// CSR build step 2: single-block chunked exclusive scan.
// On entry  cnt[i] = count of row i.
// On exit   cnt[i] = exclusive prefix (becomes the scatter cursor),
//           ptr[i] = exclusive prefix, ptr[n] = total.
// ---------------------------------------------------------------------------
__global__ __launch_bounds__(1024) void scan_excl(
    int* __restrict__ cnt, int* __restrict__ ptr, int n)
{
    __shared__ int waveSums[16];
    __shared__ int s_carry;
    int tid  = threadIdx.x;
    int lane = tid & 63;
    int wave = tid >> 6;
    if (tid == 0) { s_carry = 0; ptr[0] = 0; }
    __syncthreads();

    for (int base = 0; base < n; base += 1024) {
        int i = base + tid;
        int x = (i < n) ? cnt[i] : 0;
        int incl = x;
#pragma unroll
        for (int off = 1; off < 64; off <<= 1) {
            int y = __shfl_up(incl, off, 64);
            if (lane >= off) incl += y;
        }
        if (lane == 63) waveSums[wave] = incl;
        __syncthreads();
        if (wave == 0 && lane < 16) {
            int w = waveSums[lane];
#pragma unroll
            for (int off = 1; off < 16; off <<= 1) {
                int y = __shfl_up(w, off, 16);
                if (lane >= off) w += y;
            }
            waveSums[lane] = w;
        }
        __syncthreads();
        int waveOff  = (wave > 0) ? waveSums[wave - 1] : 0;
        int carry    = s_carry;
        int inclTot  = carry + waveOff + incl;
        if (i < n) {
            ptr[i + 1] = inclTot;
            cnt[i]     = inclTot - x;     // exclusive offset -> cursor
        }
        __syncthreads();                   // everyone done with s_carry/waveSums
        if (tid == 1023) s_carry = carry + waveSums[15];
        __syncthreads();
    }
}

// ---------------------------------------------------------------------------
// CSR build step 3: scatter (col,val) pairs into row-sorted order.
// ---------------------------------------------------------------------------
__global__ __launch_bounds__(256) void build_csr(
    const int* __restrict__ rows, const int* __restrict__ cols,
    const float* __restrict__ vals, int nnz,
    int* __restrict__ cursor, float2* __restrict__ pack)
{
    int e = blockIdx.x * blockDim.x + threadIdx.x;
    if (e >= nnz) return;
    int p = atomicAdd(&cursor[rows[e]], 1);
    pack[p] = make_float2(__int_as_float(cols[e]), vals[e]);
}

// ---------------------------------------------------------------------------
// Gather SpMM: out[r,:] = sum_j vals[j] * dense[cols[j],:]  (CSR row walk)
// 32 lanes per row, float4 per lane, register accumulate, one clean write.
// ---------------------------------------------------------------------------
__global__ __launch_bounds__(256) void spmm_gather(
    const int* __restrict__ ptr, const float2* __restrict__ pack,
    const float* __restrict__ dense, float* __restrict__ out, int nrows)
{
    long long t = (long long)blockIdx.x * blockDim.x + threadIdx.x;
    int r    = (int)(t >> 5);
    int lane = (int)(t & 31);
    if (r >= nrows) return;
    int p0 = ptr[r];
    int p1 = ptr[r + 1];
    float4 acc = make_float4(0.f, 0.f, 0.f, 0.f);
    for (int j = p0; j < p1; ++j) {
        float2 cv = pack[j];                       // broadcast across 32 lanes
        int   c = __float_as_int(cv.x);
        float v = cv.y;
        float4 x = ((const float4*)(dense + (size_t)c * DIM))[lane];
        acc.x = fmaf(v, x.x, acc.x);
        acc.y = fmaf(v, x.y, acc.y);
        acc.z = fmaf(v, x.z, acc.z);
        acc.w = fmaf(v, x.w, acc.w);
    }
    ((float4*)(out + (size_t)r * DIM))[lane] = acc;
}

// ---------------------------------------------------------------------------
// Dense layer: msg[g, d] = b[d] + sum_k concat(um,im)[g, k] * W[d, k]
// ---------------------------------------------------------------------------
__global__ __launch_bounds__(256) void dense_agg(
    const float* __restrict__ um, const float* __restrict__ im,
    const float* __restrict__ W, const float* __restrict__ b,
    float* __restrict__ msg)
{
    __shared__ float As[32][68];
    __shared__ float Ws[64][132];

    int tid = threadIdx.x;
    int tx  = tid & 15;
    int ty  = tid >> 4;
    int rowBase = blockIdx.x * 32;

    float acc[2][8];
#pragma unroll
    for (int i = 0; i < 2; ++i)
#pragma unroll
        for (int j = 0; j < 8; ++j) acc[i][j] = 0.f;

    for (int kc = 0; kc < 4; ++kc) {
        int k0 = kc * 64;
        const float* Asrc = (k0 < DIM) ? um : im;
        int kOff = (k0 < DIM) ? k0 : (k0 - DIM);

#pragma unroll
        for (int l = 0; l < 2; ++l) {
            int idx = tid + l * 256;
            int r   = idx >> 4;
            int kq  = idx & 15;
            int gRow = rowBase + r;
            float4 v = make_float4(0.f, 0.f, 0.f, 0.f);
            if (gRow < N_GROUPS)
                v = *(const float4*)(Asrc + (size_t)gRow * DIM + kOff + kq * 4);
            *(float4*)&As[r][kq * 4] = v;
        }
#pragma unroll
        for (int l = 0; l < 8; ++l) {
            int idx = tid + l * 256;
            int d   = idx >> 4;
            int kq  = idx & 15;
            float4 v = *(const float4*)(W + (size_t)d * TWO_DIM + k0 + kq * 4);
            Ws[kq * 4 + 0][d] = v.x;
            Ws[kq * 4 + 1][d] = v.y;
            Ws[kq * 4 + 2][d] = v.z;
            Ws[kq * 4 + 3][d] = v.w;
        }
        __syncthreads();

        int ty2 = ty * 2;
        int tx8 = tx * 8;
#pragma unroll 8
        for (int k = 0; k < 64; ++k) {
            float a0 = As[ty2 + 0][k];
            float a1 = As[ty2 + 1][k];
            float4 w0 = *(const float4*)&Ws[k][tx8];
            float4 w1 = *(const float4*)&Ws[k][tx8 + 4];
            acc[0][0] = fmaf(a0, w0.x, acc[0][0]);
            acc[0][1] = fmaf(a0, w0.y, acc[0][1]);
            acc[0][2] = fmaf(a0, w0.z, acc[0][2]);
            acc[0][3] = fmaf(a0, w0.w, acc[0][3]);
            acc[0][4] = fmaf(a0, w1.x, acc[0][4]);
            acc[0][5] = fmaf(a0, w1.y, acc[0][5]);
            acc[0][6] = fmaf(a0, w1.z, acc[0][6]);
            acc[0][7] = fmaf(a0, w1.w, acc[0][7]);
            acc[1][0] = fmaf(a1, w0.x, acc[1][0]);
            acc[1][1] = fmaf(a1, w0.y, acc[1][1]);
            acc[1][2] = fmaf(a1, w0.z, acc[1][2]);
            acc[1][3] = fmaf(a1, w0.w, acc[1][3]);
            acc[1][4] = fmaf(a1, w1.x, acc[1][4]);
            acc[1][5] = fmaf(a1, w1.y, acc[1][5]);
            acc[1][6] = fmaf(a1, w1.z, acc[1][6]);
            acc[1][7] = fmaf(a1, w1.w, acc[1][7]);
        }
        __syncthreads();
    }

    int d0 = tx * 8;
    float4 bv0 = *(const float4*)(b + d0);
    float4 bv1 = *(const float4*)(b + d0 + 4);
#pragma unroll
    for (int i = 0; i < 2; ++i) {
        int gRow = rowBase + ty * 2 + i;
        if (gRow < N_GROUPS) {
            float4 o0 = make_float4(acc[i][0] + bv0.x, acc[i][1] + bv0.y,
                                    acc[i][2] + bv0.z, acc[i][3] + bv0.w);
            float4 o1 = make_float4(acc[i][4] + bv1.x, acc[i][5] + bv1.y,
                                    acc[i][6] + bv1.z, acc[i][7] + bv1.w);
            *(float4*)(msg + (size_t)gRow * DIM + d0)     = o0;
            *(float4*)(msg + (size_t)gRow * DIM + d0 + 4) = o1;
        }
    }
}

// ---------------------------------------------------------------------------
extern "C" void kernel_launch(void* const* d_in, const int* in_sizes, int n_in,
                              void* d_out, int out_size, void* d_ws, size_t ws_size,
                              hipStream_t stream)
{
    const float* user_emb = (const float*)d_in[0];
    const float* item_emb = (const float*)d_in[1];
    const int*   u_rows = (const int*)d_in[3];
    const int*   u_cols = (const int*)d_in[4];
    const float* u_vals = (const float*)d_in[5];
    const int*   i_rows = (const int*)d_in[6];
    const int*   i_cols = (const int*)d_in[7];
    const float* i_vals = (const float*)d_in[8];
    const int*   f_rows = (const int*)d_in[9];
    const int*   f_cols = (const int*)d_in[10];
    const float* f_vals = (const float*)d_in[11];
    const float* W      = (const float*)d_in[12];
    const float* bias   = (const float*)d_in[13];

    int nnz_u = in_sizes[3];
    int nnz_i = in_sizes[6];
    int nnz_f = in_sizes[9];

    float* out  = (float*)d_out;
    float* norm = out;                                   // [150000, 128]
    float* msg  = out + (size_t)N_FULL * DIM;            // [20000, 128]

    // um/im scratch lives in the norm region (fully overwritten later by f-gather)
    float* um = norm;
    float* im = norm + (size_t)N_GROUPS * DIM;

    auto ceil16 = [](size_t b) { return (b + 15) & ~(size_t)15; };
    size_t need = 0;
    size_t o_u_ptr  = need; need += ceil16((N_GROUPS + 1) * 4);
    size_t o_u_cur  = need; need += ceil16((size_t)N_GROUPS * 4);
    size_t o_i_ptr  = need; need += ceil16((N_GROUPS + 1) * 4);
    size_t o_i_cur  = need; need += ceil16((size_t)N_GROUPS * 4);
    size_t o_f_ptr  = need; need += ceil16((N_FULL + 1) * 4);
    size_t o_f_cur  = need; need += ceil16((size_t)N_FULL * 4);
    size_t o_u_pack = need; need += ceil16((size_t)nnz_u * 8);
    size_t o_i_pack = need; need += ceil16((size_t)nnz_i * 8);
    size_t o_f_pack = need; need += ceil16((size_t)nnz_f * 8);

    auto eblocks = [](int n) { return (unsigned)((n + 255) / 256); };
    auto rblocks = [](int nrows) {
        return (unsigned)(((long long)nrows * 32 + 255) / 256);
    };

    if (ws_size >= need) {
        uint8_t* ws = (uint8_t*)d_ws;
        int* u_ptr = (int*)(ws + o_u_ptr);
        int* u_cur = (int*)(ws + o_u_cur);
        int* i_ptr = (int*)(ws + o_i_ptr);
        int* i_cur = (int*)(ws + o_i_cur);
        int* f_ptr = (int*)(ws + o_f_ptr);
        int* f_cur = (int*)(ws + o_f_cur);
        float2* u_pack = (float2*)(ws + o_u_pack);
        float2* i_pack = (float2*)(ws + o_i_pack);
        float2* f_pack = (float2*)(ws + o_f_pack);

        // zero the three histogram/cursor arrays
        hipMemsetAsync(u_cur, 0, (size_t)N_GROUPS * 4, stream);
        hipMemsetAsync(i_cur, 0, (size_t)N_GROUPS * 4, stream);
        hipMemsetAsync(f_cur, 0, (size_t)N_FULL * 4, stream);

        // ---- user graph CSR + gather -> um
        hist_rows<<<eblocks(nnz_u), 256, 0, stream>>>(u_rows, nnz_u, u_cur);
        scan_excl<<<1, 1024, 0, stream>>>(u_cur, u_ptr, N_GROUPS);
        build_csr<<<eblocks(nnz_u), 256, 0, stream>>>(u_rows, u_cols, u_vals,
                                                      nnz_u, u_cur, u_pack);
        spmm_gather<<<rblocks(N_GROUPS), 256, 0, stream>>>(u_ptr, u_pack,
                                                           user_emb, um, N_GROUPS);
        // ---- item graph CSR + gather -> im
        hist_rows<<<eblocks(nnz_i), 256, 0, stream>>>(i_rows, nnz_i, i_cur);
        scan_excl<<<1, 1024, 0, stream>>>(i_cur, i_ptr, N_GROUPS);
        build_csr<<<eblocks(nnz_i), 256, 0, stream>>>(i_rows, i_cols, i_vals,
                                                      nnz_i, i_cur, i_pack);
        spmm_gather<<<rblocks(N_GROUPS), 256, 0, stream>>>(i_ptr, i_pack,
                                                           item_emb, im, N_GROUPS);
        // ---- full graph CSR (independent of msg)
        hist_rows<<<eblocks(nnz_f), 256, 0, stream>>>(f_rows, nnz_f, f_cur);
        scan_excl<<<1, 1024, 0, stream>>>(f_cur, f_ptr, N_FULL);
        build_csr<<<eblocks(nnz_f), 256, 0, stream>>>(f_rows, f_cols, f_vals,
                                                      nnz_f, f_cur, f_pack);

        // ---- dense layer -> msg
        dense_agg<<<(N_GROUPS + 31) / 32, 256, 0, stream>>>(um, im, W, bias, msg);

        // ---- final gather -> norm (fully overwrites the scratch region)
        spmm_gather<<<rblocks(N_FULL), 256, 0, stream>>>(f_ptr, f_pack,
                                                         msg, norm, N_FULL);
    } else {
        // Fallback: R1 atomic path
        hipMemsetAsync(norm, 0, (size_t)N_FULL * DIM * sizeof(float), stream);
        auto spmm_blocks = [](int nnz) {
            return (unsigned)(((long long)nnz * 32 + 255) / 256);
        };
        spmm_atomic<<<spmm_blocks(nnz_u), 256, 0, stream>>>(
            u_rows, u_cols, u_vals, user_emb, um, nnz_u);
        spmm_atomic<<<spmm_blocks(nnz_i), 256, 0, stream>>>(
            i_rows, i_cols, i_vals, item_emb, im, nnz_i);
        dense_agg<<<(N_GROUPS + 31) / 32, 256, 0, stream>>>(um, im, W, bias, msg);
        hipMemsetAsync(norm, 0, (size_t)2 * N_GROUPS * DIM * sizeof(float), stream);
        spmm_atomic<<<spmm_blocks(nnz_f), 256, 0, stream>>>(
            f_rows, f_cols, f_vals, msg, norm, nnz_f);
    }
}

// Round 3
// 1220.665 us; speedup vs baseline: 8.3538x; 1.2355x over previous
//
#include <hip/hip_runtime.h>
#include <hip/hip_bf16.h>
#include <stdint.h>

// Problem dims (fixed by reference)
#define N_USERS  50000
#define N_ITEMS  100000
#define N_GROUPS 20000
#define DIM      128
#define TWO_DIM  256
#define N_FULL   (N_USERS + N_ITEMS)   // 150000

// ---------------------------------------------------------------------------
// Fallback path (R1): SpMM scatter with f32 atomics.
// ---------------------------------------------------------------------------
__global__ __launch_bounds__(256) void spmm_atomic(
    const int* __restrict__ rows, const int* __restrict__ cols,
    const float* __restrict__ vals, const float* __restrict__ dense,
    float* __restrict__ out, int nnz)
{
    long long t = (long long)blockIdx.x * blockDim.x + threadIdx.x;
    int e    = (int)(t >> 5);
    int lane = (int)(t & 31);
    if (e >= nnz) return;
    int   r = rows[e];
    int   c = cols[e];
    float v = vals[e];
    float4 x = ((const float4*)(dense + (size_t)c * DIM))[lane];
    float* dst = out + (size_t)r * DIM + lane * 4;
    atomicAdd(dst + 0, v * x.x);
    atomicAdd(dst + 1, v * x.y);
    atomicAdd(dst + 2, v * x.z);
    atomicAdd(dst + 3, v * x.w);
}

// ---------------------------------------------------------------------------
// Fused histogram over all three edge lists (int atomics, L2-resident cnts).
// ---------------------------------------------------------------------------
__global__ __launch_bounds__(256) void hist_all(
    const int* __restrict__ u_rows, int nnz_u, int* __restrict__ u_cnt,
    const int* __restrict__ i_rows, int nnz_i, int* __restrict__ i_cnt,
    const int* __restrict__ f_rows, int nnz_f, int* __restrict__ f_cnt)
{
    long long t = (long long)blockIdx.x * blockDim.x + threadIdx.x;
    if (t < nnz_u) {
        atomicAdd(&u_cnt[u_rows[t]], 1);
    } else if (t < (long long)nnz_u + nnz_i) {
        atomicAdd(&i_cnt[i_rows[t - nnz_u]], 1);
    } else if (t < (long long)nnz_u + nnz_i + nnz_f) {
        atomicAdd(&f_cnt[f_rows[t - nnz_u - nnz_i]], 1);
    }
}

// ---------------------------------------------------------------------------
// Multi-block exclusive scan, batched over 3 arrays.
// Each block covers 1024 elements (256 thr x 4). Three kernels:
//   scan_partials: per-block sums -> bs[]
//   scan_bsums:    exclusive-scan each bs[] (single block, nb<=256)
//   scan_apply:    block-local scan + bs offset; writes cursor (in cnt) and ptr
// ---------------------------------------------------------------------------
__device__ inline void seg_map(int b, int nb_u, int nb_i,
                               int* __restrict__ u_cnt, int* __restrict__ i_cnt, int* __restrict__ f_cnt,
                               int* __restrict__ bs_u, int* __restrict__ bs_i, int* __restrict__ bs_f,
                               int n_u, int n_f,
                               int*& cnt, int*& bs, int& n, int& lb, int& seg)
{
    if (b < nb_u)              { cnt = u_cnt; bs = bs_u; n = n_u; lb = b;              seg = 0; }
    else if (b < nb_u + nb_i)  { cnt = i_cnt; bs = bs_i; n = n_u; lb = b - nb_u;       seg = 1; }
    else                       { cnt = f_cnt; bs = bs_f; n = n_f; lb = b - nb_u - nb_i; seg = 2; }
}

__device__ inline int4 load4_guard(const int* __restrict__ p, int idx, int n)
{
    int4 x = make_int4(0, 0, 0, 0);
    if (idx + 3 < n) x = *(const int4*)(p + idx);
    else {
        if (idx     < n) x.x = p[idx];
        if (idx + 1 < n) x.y = p[idx + 1];
        if (idx + 2 < n) x.z = p[idx + 2];
    }
    return x;
}

__global__ __launch_bounds__(256) void scan_partials(
    int* __restrict__ u_cnt, int* __restrict__ i_cnt, int* __restrict__ f_cnt,
    int* __restrict__ bs_u, int* __restrict__ bs_i, int* __restrict__ bs_f,
    int nb_u, int nb_i, int n_u, int n_f)
{
    __shared__ int wsum[4];
    int *cnt, *bs; int n, lb, seg;
    seg_map(blockIdx.x, nb_u, nb_i, u_cnt, i_cnt, f_cnt, bs_u, bs_i, bs_f,
            n_u, n_f, cnt, bs, n, lb, seg);
    int tid  = threadIdx.x;
    int lane = tid & 63;
    int wave = tid >> 6;
    int idx  = lb * 1024 + tid * 4;
    int4 x = load4_guard(cnt, idx, n);
    int s = x.x + x.y + x.z + x.w;
#pragma unroll
    for (int off = 32; off; off >>= 1) s += __shfl_down(s, off, 64);
    if (lane == 0) wsum[wave] = s;
    __syncthreads();
    if (tid == 0) bs[lb] = wsum[0] + wsum[1] + wsum[2] + wsum[3];
}

__global__ __launch_bounds__(256) void scan_bsums(
    int* __restrict__ bs0, int n0, int* __restrict__ bs1, int n1,
    int* __restrict__ bs2, int n2)
{
    __shared__ int wsum[4];
    int tid = threadIdx.x, lane = tid & 63, wave = tid >> 6;
    int* arr[3] = {bs0, bs1, bs2};
    int  ns[3]  = {n0, n1, n2};
    for (int s3 = 0; s3 < 3; ++s3) {
        int* bs = arr[s3];
        int  nb = ns[s3];
        int x = (tid < nb) ? bs[tid] : 0;
        int incl = x;
#pragma unroll
        for (int off = 1; off < 64; off <<= 1) {
            int y = __shfl_up(incl, off, 64);
            if (lane >= off) incl += y;
        }
        if (lane == 63) wsum[wave] = incl;
        __syncthreads();
        int waveOff = 0;
        for (int w = 0; w < wave; ++w) waveOff += wsum[w];
        if (tid < nb) bs[tid] = waveOff + incl - x;   // exclusive
        __syncthreads();
    }
}

__global__ __launch_bounds__(256) void scan_apply(
    int* __restrict__ u_cnt, int* __restrict__ i_cnt, int* __restrict__ f_cnt,
    int* __restrict__ bs_u, int* __restrict__ bs_i, int* __restrict__ bs_f,
    int* __restrict__ u_ptr, int* __restrict__ i_ptr, int* __restrict__ f_ptr,
    int nb_u, int nb_i, int n_u, int n_f)
{
    __shared__ int wsum[4];
    int *cnt, *bs; int n, lb, seg;
    seg_map(blockIdx.x, nb_u, nb_i, u_cnt, i_cnt, f_cnt, bs_u, bs_i, bs_f,
            n_u, n_f, cnt, bs, n, lb, seg);
    int* ptr = (seg == 0) ? u_ptr : (seg == 1) ? i_ptr : f_ptr;
    int tid  = threadIdx.x;
    int lane = tid & 63;
    int wave = tid >> 6;
    int idx  = lb * 1024 + tid * 4;
    int4 x = load4_guard(cnt, idx, n);
    int s = x.x + x.y + x.z + x.w;
    int incl = s;
#pragma unroll
    for (int off = 1; off < 64; off <<= 1) {
        int y = __shfl_up(incl, off, 64);
        if (lane >= off) incl += y;
    }
    if (lane == 63) wsum[wave] = incl;
    __syncthreads();
    int waveOff = 0;
    for (int w = 0; w < wave; ++w) waveOff += wsum[w];
    int e0 = bs[lb] + waveOff + incl - s;   // exclusive prefix of element idx
    int e1 = e0 + x.x;
    int e2 = e1 + x.y;
    int e3 = e2 + x.z;
    if (idx     < n) { cnt[idx]     = e0; ptr[idx + 1] = e1; }
    if (idx + 1 < n) { cnt[idx + 1] = e1; ptr[idx + 2] = e2; }
    if (idx + 2 < n) { cnt[idx + 2] = e2; ptr[idx + 3] = e3; }
    if (idx + 3 < n) { cnt[idx + 3] = e3; ptr[idx + 4] = e3 + x.w; }
    if (lb == 0 && tid == 0) ptr[0] = 0;
}

// ---------------------------------------------------------------------------
// Fused CSR build: scatter (col,val) pairs into row-sorted order, all graphs.
// ---------------------------------------------------------------------------
__global__ __launch_bounds__(256) void build_all(
    const int* __restrict__ u_rows, const int* __restrict__ u_cols,
    const float* __restrict__ u_vals, int nnz_u,
    int* __restrict__ u_cur, float2* __restrict__ u_pack,
    const int* __restrict__ i_rows, const int* __restrict__ i_cols,
    const float* __restrict__ i_vals, int nnz_i,
    int* __restrict__ i_cur, float2* __restrict__ i_pack,
    const int* __restrict__ f_rows, const int* __restrict__ f_cols,
    const float* __restrict__ f_vals, int nnz_f,
    int* __restrict__ f_cur, float2* __restrict__ f_pack)
{
    long long t = (long long)blockIdx.x * blockDim.x + threadIdx.x;
    if (t < nnz_u) {
        int e = (int)t;
        int p = atomicAdd(&u_cur[u_rows[e]], 1);
        u_pack[p] = make_float2(__int_as_float(u_cols[e]), u_vals[e]);
    } else if (t < (long long)nnz_u + nnz_i) {
        int e = (int)(t - nnz_u);
        int p = atomicAdd(&i_cur[i_rows[e]], 1);
        i_pack[p] = make_float2(__int_as_float(i_cols[e]), i_vals[e]);
    } else if (t < (long long)nnz_u + nnz_i + nnz_f) {
        int e = (int)(t - nnz_u - nnz_i);
        int p = atomicAdd(&f_cur[f_rows[e]], 1);
        f_pack[p] = make_float2(__int_as_float(f_cols[e]), f_vals[e]);
    }
}

// ---------------------------------------------------------------------------
// Gather SpMM row walk, unrolled x4 with 4 independent accumulators (MLP).
// 32 lanes per row, float4 per lane.
// ---------------------------------------------------------------------------
__device__ inline void gather_row(
    const int* __restrict__ ptr, const float2* __restrict__ pack,
    const float* __restrict__ dense, float* __restrict__ out, int r, int lane)
{
    int p0 = ptr[r];
    int p1 = ptr[r + 1];
    float4 a0 = make_float4(0.f, 0.f, 0.f, 0.f);
    float4 a1 = a0, a2 = a0, a3 = a0;
    int j = p0;
    for (; j + 4 <= p1; j += 4) {
        float2 cv0 = pack[j + 0];
        float2 cv1 = pack[j + 1];
        float2 cv2 = pack[j + 2];
        float2 cv3 = pack[j + 3];
        float4 x0 = ((const float4*)(dense + (size_t)__float_as_int(cv0.x) * DIM))[lane];
        float4 x1 = ((const float4*)(dense + (size_t)__float_as_int(cv1.x) * DIM))[lane];
        float4 x2 = ((const float4*)(dense + (size_t)__float_as_int(cv2.x) * DIM))[lane];
        float4 x3 = ((const float4*)(dense + (size_t)__float_as_int(cv3.x) * DIM))[lane];
        a0.x = fmaf(cv0.y, x0.x, a0.x); a0.y = fmaf(cv0.y, x0.y, a0.y);
        a0.z = fmaf(cv0.y, x0.z, a0.z); a0.w = fmaf(cv0.y, x0.w, a0.w);
        a1.x = fmaf(cv1.y, x1.x, a1.x); a1.y = fmaf(cv1.y, x1.y, a1.y);
        a1.z = fmaf(cv1.y, x1.z, a1.z); a1.w = fmaf(cv1.y, x1.w, a1.w);
        a2.x = fmaf(cv2.y, x2.x, a2.x); a2.y = fmaf(cv2.y, x2.y, a2.y);
        a2.z = fmaf(cv2.y, x2.z, a2.z); a2.w = fmaf(cv2.y, x2.w, a2.w);
        a3.x = fmaf(cv3.y, x3.x, a3.x); a3.y = fmaf(cv3.y, x3.y, a3.y);
        a3.z = fmaf(cv3.y, x3.z, a3.z); a3.w = fmaf(cv3.y, x3.w, a3.w);
    }
    for (; j < p1; ++j) {
        float2 cv = pack[j];
        float4 x = ((const float4*)(dense + (size_t)__float_as_int(cv.x) * DIM))[lane];
        a0.x = fmaf(cv.y, x.x, a0.x); a0.y = fmaf(cv.y, x.y, a0.y);
        a0.z = fmaf(cv.y, x.z, a0.z); a0.w = fmaf(cv.y, x.w, a0.w);
    }
    float4 acc;
    acc.x = (a0.x + a1.x) + (a2.x + a3.x);
    acc.y = (a0.y + a1.y) + (a2.y + a3.y);
    acc.z = (a0.z + a1.z) + (a2.z + a3.z);
    acc.w = (a0.w + a1.w) + (a2.w + a3.w);
    ((float4*)(out + (size_t)r * DIM))[lane] = acc;
}

__global__ __launch_bounds__(256) void gather_ui(
    const int* __restrict__ u_ptr, const float2* __restrict__ u_pack,
    const float* __restrict__ user_emb, float* __restrict__ um,
    const int* __restrict__ i_ptr, const float2* __restrict__ i_pack,
    const float* __restrict__ item_emb, float* __restrict__ im)
{
    long long t = (long long)blockIdx.x * blockDim.x + threadIdx.x;
    int r    = (int)(t >> 5);
    int lane = (int)(t & 31);
    if (r < N_GROUPS)
        gather_row(u_ptr, u_pack, user_emb, um, r, lane);
    else if (r < 2 * N_GROUPS)
        gather_row(i_ptr, i_pack, item_emb, im, r - N_GROUPS, lane);
}

__global__ __launch_bounds__(256) void gather_f(
    const int* __restrict__ f_ptr, const float2* __restrict__ f_pack,
    const float* __restrict__ msg, float* __restrict__ norm)
{
    long long t = (long long)blockIdx.x * blockDim.x + threadIdx.x;
    int r    = (int)(t >> 5);
    int lane = (int)(t & 31);
    if (r < N_FULL)
        gather_row(f_ptr, f_pack, msg, norm, r, lane);
}

// ---------------------------------------------------------------------------
// Dense layer: msg[g, d] = b[d] + sum_k concat(um,im)[g, k] * W[d, k]
// ---------------------------------------------------------------------------
__global__ __launch_bounds__(256) void dense_agg(
    const float* __restrict__ um, const float* __restrict__ im,
    const float* __restrict__ W, const float* __restrict__ b,
    float* __restrict__ msg)
{
    __shared__ float As[32][68];
    __shared__ float Ws[64][132];

    int tid = threadIdx.x;
    int tx  = tid & 15;
    int ty  = tid >> 4;
    int rowBase = blockIdx.x * 32;

    float acc[2][8];
#pragma unroll
    for (int i = 0; i < 2; ++i)
#pragma unroll
        for (int j = 0; j < 8; ++j) acc[i][j] = 0.f;

    for (int kc = 0; kc < 4; ++kc) {
        int k0 = kc * 64;
        const float* Asrc = (k0 < DIM) ? um : im;
        int kOff = (k0 < DIM) ? k0 : (k0 - DIM);

#pragma unroll
        for (int l = 0; l < 2; ++l) {
            int idx = tid + l * 256;
            int r   = idx >> 4;
            int kq  = idx & 15;
            int gRow = rowBase + r;
            float4 v = make_float4(0.f, 0.f, 0.f, 0.f);
            if (gRow < N_GROUPS)
                v = *(const float4*)(Asrc + (size_t)gRow * DIM + kOff + kq * 4);
            *(float4*)&As[r][kq * 4] = v;
        }
#pragma unroll
        for (int l = 0; l < 8; ++l) {
            int idx = tid + l * 256;
            int d   = idx >> 4;
            int kq  = idx & 15;
            float4 v = *(const float4*)(W + (size_t)d * TWO_DIM + k0 + kq * 4);
            Ws[kq * 4 + 0][d] = v.x;
            Ws[kq * 4 + 1][d] = v.y;
            Ws[kq * 4 + 2][d] = v.z;
            Ws[kq * 4 + 3][d] = v.w;
        }
        __syncthreads();

        int ty2 = ty * 2;
        int tx8 = tx * 8;
#pragma unroll 8
        for (int k = 0; k < 64; ++k) {
            float a0 = As[ty2 + 0][k];
            float a1 = As[ty2 + 1][k];
            float4 w0 = *(const float4*)&Ws[k][tx8];
            float4 w1 = *(const float4*)&Ws[k][tx8 + 4];
            acc[0][0] = fmaf(a0, w0.x, acc[0][0]);
            acc[0][1] = fmaf(a0, w0.y, acc[0][1]);
            acc[0][2] = fmaf(a0, w0.z, acc[0][2]);
            acc[0][3] = fmaf(a0, w0.w, acc[0][3]);
            acc[0][4] = fmaf(a0, w1.x, acc[0][4]);
            acc[0][5] = fmaf(a0, w1.y, acc[0][5]);
            acc[0][6] = fmaf(a0, w1.z, acc[0][6]);
            acc[0][7] = fmaf(a0, w1.w, acc[0][7]);
            acc[1][0] = fmaf(a1, w0.x, acc[1][0]);
            acc[1][1] = fmaf(a1, w0.y, acc[1][1]);
            acc[1][2] = fmaf(a1, w0.z, acc[1][2]);
            acc[1][3] = fmaf(a1, w0.w, acc[1][3]);
            acc[1][4] = fmaf(a1, w1.x, acc[1][4]);
            acc[1][5] = fmaf(a1, w1.y, acc[1][5]);
            acc[1][6] = fmaf(a1, w1.z, acc[1][6]);
            acc[1][7] = fmaf(a1, w1.w, acc[1][7]);
        }
        __syncthreads();
    }

    int d0 = tx * 8;
    float4 bv0 = *(const float4*)(b + d0);
    float4 bv1 = *(const float4*)(b + d0 + 4);
#pragma unroll
    for (int i = 0; i < 2; ++i) {
        int gRow = rowBase + ty * 2 + i;
        if (gRow < N_GROUPS) {
            float4 o0 = make_float4(acc[i][0] + bv0.x, acc[i][1] + bv0.y,
                                    acc[i][2] + bv0.z, acc[i][3] + bv0.w);
            float4 o1 = make_float4(acc[i][4] + bv1.x, acc[i][5] + bv1.y,
                                    acc[i][6] + bv1.z, acc[i][7] + bv1.w);
            *(float4*)(msg + (size_t)gRow * DIM + d0)     = o0;
            *(float4*)(msg + (size_t)gRow * DIM + d0 + 4) = o1;
        }
    }
}

// ---------------------------------------------------------------------------
extern "C" void kernel_launch(void* const* d_in, const int* in_sizes, int n_in,
                              void* d_out, int out_size, void* d_ws, size_t ws_size,
                              hipStream_t stream)
{
    const float* user_emb = (const float*)d_in[0];
    const float* item_emb = (const float*)d_in[1];
    const int*   u_rows = (const int*)d_in[3];
    const int*   u_cols = (const int*)d_in[4];
    const float* u_vals = (const float*)d_in[5];
    const int*   i_rows = (const int*)d_in[6];
    const int*   i_cols = (const int*)d_in[7];
    const float* i_vals = (const float*)d_in[8];
    const int*   f_rows = (const int*)d_in[9];
    const int*   f_cols = (const int*)d_in[10];
    const float* f_vals = (const float*)d_in[11];
    const float* W      = (const float*)d_in[12];
    const float* bias   = (const float*)d_in[13];

    int nnz_u = in_sizes[3];
    int nnz_i = in_sizes[6];
    int nnz_f = in_sizes[9];

    float* out  = (float*)d_out;
    float* norm = out;                                   // [150000, 128]
    float* msg  = out + (size_t)N_FULL * DIM;            // [20000, 128]

    // um/im scratch lives in the norm region (fully overwritten later by gather_f)
    float* um = norm;
    float* im = norm + (size_t)N_GROUPS * DIM;

    const int nb_u = (N_GROUPS + 1023) / 1024;   // 20
    const int nb_f = (N_FULL   + 1023) / 1024;   // 147

    auto ceil16 = [](size_t b) { return (b + 15) & ~(size_t)15; };
    size_t need = 0;
    size_t o_u_ptr  = need; need += ceil16((N_GROUPS + 1) * 4);
    size_t o_u_cur  = need; need += ceil16((size_t)N_GROUPS * 4);
    size_t o_i_ptr  = need; need += ceil16((N_GROUPS + 1) * 4);
    size_t o_i_cur  = need; need += ceil16((size_t)N_GROUPS * 4);
    size_t o_f_ptr  = need; need += ceil16((N_FULL + 1) * 4);
    size_t o_f_cur  = need; need += ceil16((size_t)N_FULL * 4);
    size_t o_bs_u   = need; need += ceil16((size_t)nb_u * 4);
    size_t o_bs_i   = need; need += ceil16((size_t)nb_u * 4);
    size_t o_bs_f   = need; need += ceil16((size_t)nb_f * 4);
    size_t o_u_pack = need; need += ceil16((size_t)nnz_u * 8);
    size_t o_i_pack = need; need += ceil16((size_t)nnz_i * 8);
    size_t o_f_pack = need; need += ceil16((size_t)nnz_f * 8);

    auto eblocks = [](long long n) { return (unsigned)((n + 255) / 256); };
    auto rblocks = [](long long nrows) { return (unsigned)((nrows * 32 + 255) / 256); };

    if (ws_size >= need) {
        uint8_t* ws = (uint8_t*)d_ws;
        int* u_ptr = (int*)(ws + o_u_ptr);
        int* u_cur = (int*)(ws + o_u_cur);
        int* i_ptr = (int*)(ws + o_i_ptr);
        int* i_cur = (int*)(ws + o_i_cur);
        int* f_ptr = (int*)(ws + o_f_ptr);
        int* f_cur = (int*)(ws + o_f_cur);
        int* bs_u  = (int*)(ws + o_bs_u);
        int* bs_i  = (int*)(ws + o_bs_i);
        int* bs_f  = (int*)(ws + o_bs_f);
        float2* u_pack = (float2*)(ws + o_u_pack);
        float2* i_pack = (float2*)(ws + o_i_pack);
        float2* f_pack = (float2*)(ws + o_f_pack);

        long long nnz_tot = (long long)nnz_u + nnz_i + nnz_f;

        // zero histogram/cursor arrays
        hipMemsetAsync(u_cur, 0, (size_t)N_GROUPS * 4, stream);
        hipMemsetAsync(i_cur, 0, (size_t)N_GROUPS * 4, stream);
        hipMemsetAsync(f_cur, 0, (size_t)N_FULL * 4, stream);

        // histogram (all graphs)
        hist_all<<<eblocks(nnz_tot), 256, 0, stream>>>(
            u_rows, nnz_u, u_cur, i_rows, nnz_i, i_cur, f_rows, nnz_f, f_cur);

        // batched multi-block exclusive scan -> cursors (in *_cur) and *_ptr
        scan_partials<<<nb_u + nb_u + nb_f, 256, 0, stream>>>(
            u_cur, i_cur, f_cur, bs_u, bs_i, bs_f, nb_u, nb_u, N_GROUPS, N_FULL);
        scan_bsums<<<1, 256, 0, stream>>>(bs_u, nb_u, bs_i, nb_u, bs_f, nb_f);
        scan_apply<<<nb_u + nb_u + nb_f, 256, 0, stream>>>(
            u_cur, i_cur, f_cur, bs_u, bs_i, bs_f, u_ptr, i_ptr, f_ptr,
            nb_u, nb_u, N_GROUPS, N_FULL);

        // CSR build (all graphs)
        build_all<<<eblocks(nnz_tot), 256, 0, stream>>>(
            u_rows, u_cols, u_vals, nnz_u, u_cur, u_pack,
            i_rows, i_cols, i_vals, nnz_i, i_cur, i_pack,
            f_rows, f_cols, f_vals, nnz_f, f_cur, f_pack);

        // gathers u+i -> um, im
        gather_ui<<<rblocks(2 * N_GROUPS), 256, 0, stream>>>(
            u_ptr, u_pack, user_emb, um, i_ptr, i_pack, item_emb, im);

        // dense layer -> msg
        dense_agg<<<(N_GROUPS + 31) / 32, 256, 0, stream>>>(um, im, W, bias, msg);

        // final gather -> norm (fully overwrites scratch region)
        gather_f<<<rblocks(N_FULL), 256, 0, stream>>>(f_ptr, f_pack, msg, norm);
    } else {
        // Fallback: R1 atomic path
        hipMemsetAsync(norm, 0, (size_t)N_FULL * DIM * sizeof(float), stream);
        auto spmm_blocks = [](int nnz) {
            return (unsigned)(((long long)nnz * 32 + 255) / 256);
        };
        spmm_atomic<<<spmm_blocks(nnz_u), 256, 0, stream>>>(
            u_rows, u_cols, u_vals, user_emb, um, nnz_u);
        spmm_atomic<<<spmm_blocks(nnz_i), 256, 0, stream>>>(
            i_rows, i_cols, i_vals, item_emb, im, nnz_i);
        dense_agg<<<(N_GROUPS + 31) / 32, 256, 0, stream>>>(um, im, W, bias, msg);
        hipMemsetAsync(norm, 0, (size_t)2 * N_GROUPS * DIM * sizeof(float), stream);
        spmm_atomic<<<spmm_blocks(nnz_f), 256, 0, stream>>>(
            f_rows, f_cols, f_vals, msg, norm, nnz_f);
    }
}